// Round 1
// baseline (261.265 us; speedup 1.0000x reference)
//
#include <hip/hip_runtime.h>

// DigitCaps dynamic routing, B=512, N=4608, IN=16, OUT=32, CAPS=32.
// Key identity: with b-logits initialized to zero, softmax stays exactly
// uniform (1/32) across all 3 routing iterations (v is c-independent, so the
// agreement update is constant across c, so softmax(b) stays uniform).
// Hence: v[b,c,k] = squash_k((1/32) * sum_{n,j} x[b,n,j]*W[n,j,k]), all c.
// => one GEMM  S[512,32] = X[512,73728] @ Wflat[73728,32], squash, broadcast.

#define NB 512
#define KTOT 73728          // N*IN = 4608*16
#define OUTC 32
#define NCAPS 32

#define KSPLIT 16
#define KCHUNK (KTOT / KSPLIT)   // 4608
#define KT 256                   // K-tile staged in LDS
#define NTILES (KCHUNK / KT)     // 18
#define RPW 4                    // rows per wave
#define NWAVES 4
#define RPB (RPW * NWAVES)       // 16 rows per block
#define NRG (NB / RPB)           // 32 row-groups
#define LSTR 33                  // LDS row stride (pad +1: (k+c)%32 banks, 2-way = free)

__global__ __launch_bounds__(256) void zero_ws(float* __restrict__ S) {
    int i = blockIdx.x * 256 + threadIdx.x;
    if (i < NB * OUTC) S[i] = 0.0f;
}

__global__ __launch_bounds__(256, 2) void gemm_splitk(
        const float* __restrict__ x, const float* __restrict__ w,
        float* __restrict__ S) {
    __shared__ float wlds[KT * LSTR];   // 33792 B
    const int t = threadIdx.x;
    const int lane = t & 63;
    const int wave = t >> 6;
    const int row0 = blockIdx.x * RPB + wave * RPW;
    const size_t kbase = (size_t)blockIdx.y * KCHUNK;

    float acc[RPW][OUTC];
#pragma unroll
    for (int r = 0; r < RPW; ++r)
#pragma unroll
        for (int c = 0; c < OUTC; ++c) acc[r][c] = 0.0f;

    const float* xp[RPW];
#pragma unroll
    for (int r = 0; r < RPW; ++r)
        xp[r] = x + (size_t)(row0 + r) * KTOT + kbase;

    for (int tile = 0; tile < NTILES; ++tile) {
        // ---- cooperative stage of W[kb .. kb+256)[0..32) into LDS ----
        const float4* wv = (const float4*)(w + (kbase + (size_t)tile * KT) * OUTC);
#pragma unroll
        for (int j = 0; j < 8; ++j) {
            int f = j * 256 + t;     // float4 index within 256x32 tile
            int kk = f >> 3;         // k row 0..255
            int g  = f & 7;          // group-of-4 column
            float4 v = wv[f];
            float* dst = &wlds[kk * LSTR + g * 4];
            dst[0] = v.x; dst[1] = v.y; dst[2] = v.z; dst[3] = v.w;
        }
        __syncthreads();

        // ---- compute: lane covers k = lane + 64*i; 4 rows x 32 cols FMA ----
#pragma unroll
        for (int i = 0; i < KT / 64; ++i) {
            const int kl = lane + i * 64;
            float xr[RPW];
#pragma unroll
            for (int r = 0; r < RPW; ++r)
                xr[r] = xp[r][tile * KT + kl];   // coalesced: lanes = consecutive k
            const float* wrow = &wlds[kl * LSTR];
#pragma unroll
            for (int c = 0; c < OUTC; ++c) {
                const float wc = wrow[c];
#pragma unroll
                for (int r = 0; r < RPW; ++r)
                    acc[r][c] = fmaf(xr[r], wc, acc[r][c]);
            }
        }
        __syncthreads();
    }

    // ---- reduce acc over 64 lanes, one atomicAdd per (row, c) ----
#pragma unroll
    for (int r = 0; r < RPW; ++r) {
        float myv = 0.0f;
#pragma unroll
        for (int c = 0; c < OUTC; ++c) {
            float v = acc[r][c];
            v += __shfl_xor(v, 32, 64);
            v += __shfl_xor(v, 16, 64);
            v += __shfl_xor(v, 8, 64);
            v += __shfl_xor(v, 4, 64);
            v += __shfl_xor(v, 2, 64);
            v += __shfl_xor(v, 1, 64);
            if (lane == c) myv = v;   // lane c keeps column c's total
        }
        if (lane < OUTC)
            atomicAdd(&S[(size_t)(row0 + r) * OUTC + lane], myv);
    }
}

__global__ __launch_bounds__(64) void finalize(const float* __restrict__ S,
                                               float* __restrict__ out) {
    const int b = blockIdx.x;
    const int t = threadIdx.x;
    const int k = t & 31;
    const int half = t >> 5;
    float s = S[b * OUTC + k] * (1.0f / 32.0f);
    float sq = s * s;
    // reduce over the 32 k-lanes (xor<=16 stays within each 32-half)
    sq += __shfl_xor(sq, 16, 64);
    sq += __shfl_xor(sq, 8, 64);
    sq += __shfl_xor(sq, 4, 64);
    sq += __shfl_xor(sq, 2, 64);
    sq += __shfl_xor(sq, 1, 64);
    // squash: v = (sq/(1+sq)) * s / sqrt(sq)
    float scale = sq / ((1.0f + sq) * sqrtf(sq));
    float v = s * scale;
    float* orow = out + (size_t)b * (NCAPS * OUTC);
#pragma unroll
    for (int j = 0; j < 16; ++j) {
        int c = half + j * 2;
        orow[c * OUTC + k] = v;      // broadcast across all capsules
    }
}

extern "C" void kernel_launch(void* const* d_in, const int* in_sizes, int n_in,
                              void* d_out, int out_size, void* d_ws, size_t ws_size,
                              hipStream_t stream) {
    const float* x = (const float*)d_in[0];          // [512, 4608, 16] f32
    const float* w = (const float*)d_in[1];          // [4608, 16, 32] f32
    float* out = (float*)d_out;                      // [512, 32, 32] f32
    float* S = (float*)d_ws;                         // [512, 32] f32 accumulator

    hipLaunchKernelGGL(zero_ws, dim3((NB * OUTC + 255) / 256), dim3(256), 0, stream, S);
    hipLaunchKernelGGL(gemm_splitk, dim3(NRG, KSPLIT), dim3(256), 0, stream, x, w, S);
    hipLaunchKernelGGL(finalize, dim3(NB), dim3(64), 0, stream, S, out);
}